// Round 1
// baseline (2864.176 us; speedup 1.0000x reference)
//
#include <hip/hip_runtime.h>
#include <math.h>

#define NT 12000
#define NO 24000
#define RANKC 32
#define KORD 10
#define E0C 384000
#define E1C 384000
#define E2C 192000

static __device__ __forceinline__ float waveSum(float v) {
  v += __shfl_xor(v, 32, 64);
  v += __shfl_xor(v, 16, 64);
  v += __shfl_xor(v, 8, 64);
  v += __shfl_xor(v, 4, 64);
  v += __shfl_xor(v, 2, 64);
  v += __shfl_xor(v, 1, 64);
  return v;
}

__global__ void k_deg(const int* __restrict__ idx, float* __restrict__ deg, int E) {
  int i = blockIdx.x * blockDim.x + threadIdx.x;
  if (i < E) atomicAdd(&deg[idx[i]], 1.0f);
}

__global__ void k_rs(float* __restrict__ d, int n) {
  int i = blockIdx.x * blockDim.x + threadIdx.x;
  if (i < n) d[i] = 1.0f / sqrtf(fmaxf(d[i], 1.0f));
}

// out[n][c] = sum_k X[n][k]*W[k][c] + b[c]; 4 rows/block, 64 cols
template<int K>
__global__ void k_gemmN64(const float* __restrict__ X, const float* __restrict__ W,
                          const float* __restrict__ b, float* __restrict__ out, int N) {
  int row = blockIdx.x * 4 + (threadIdx.x >> 6);
  int c = threadIdx.x & 63;
  if (row >= N) return;
  const float* x = X + (size_t)row * K;
  float acc = b[c];
#pragma unroll 2
  for (int k = 0; k < K; ++k) acc = fmaf(x[k], W[k * 64 + c], acc);
  out[(size_t)row * 64 + c] = acc;
}

// out[n][c] = rs[n]*sum_k A[n][k]*W[k][c] + b[c]
__global__ void k_gemm64s(const float* __restrict__ A, const float* __restrict__ rs,
                          const float* __restrict__ W, const float* __restrict__ b,
                          float* __restrict__ out, int N) {
  int row = blockIdx.x * 4 + (threadIdx.x >> 6);
  int c = threadIdx.x & 63;
  if (row >= N) return;
  const float* a = A + (size_t)row * 64;
  float acc = 0.f;
#pragma unroll
  for (int k = 0; k < 64; ++k) acc = fmaf(a[k], W[k * 64 + c], acc);
  out[(size_t)row * 64 + c] = fmaf(rs[row], acc, b[c]);
}

// agg[dst[e]][c] += X[src[e]][c] * rss[src[e]]
__global__ void k_scatter(const float* __restrict__ X, const float* __restrict__ rss,
                          const int* __restrict__ src, const int* __restrict__ dst,
                          float* __restrict__ agg, int E) {
  long long total = (long long)E * 64;
  long long stride = (long long)gridDim.x * blockDim.x;
  for (long long idx = (long long)blockIdx.x * blockDim.x + threadIdx.x; idx < total; idx += stride) {
    int e = (int)(idx >> 6);
    int c = (int)(idx & 63);
    int s = src[e];
    atomicAdd(&agg[(size_t)dst[e] * 64 + c], X[(size_t)s * 64 + c] * rss[s]);
  }
}

// accum += sum_n sum_c v[c]*tanh(fc(M[n])[c])   (divide by N later)
__global__ void k_attscore(const float* __restrict__ M, const float* __restrict__ fcW,
                           const float* __restrict__ fcb, const float* __restrict__ v,
                           float* __restrict__ accum, int N) {
  int row = blockIdx.x * 4 + (threadIdx.x >> 6);
  int c = threadIdx.x & 63;
  float part = 0.f;
  if (row < N) {
    const float* m = M + (size_t)row * 64;
    float acc = fcb[c];
#pragma unroll
    for (int k = 0; k < 64; ++k) acc = fmaf(m[k], fcW[k * 64 + c], acc);
    part = tanhf(acc) * v[c];
  }
  part = waveSum(part);
  __shared__ float sred[4];
  if ((threadIdx.x & 63) == 0) sred[threadIdx.x >> 6] = part;
  __syncthreads();
  if (threadIdx.x == 0) atomicAdd(accum, sred[0] + sred[1] + sred[2] + sred[3]);
}

// z = softmax([sc0,sc1]*invN) combo; out = cheb ? 2z - Tx0 : z
__global__ void k_combine(const float* __restrict__ m0, const float* __restrict__ m1,
                          const float* __restrict__ sc, float invN,
                          const float* __restrict__ Tx0, float* __restrict__ out,
                          int total, int cheb) {
  int i = blockIdx.x * blockDim.x + threadIdx.x;
  if (i >= total) return;
  float s0 = sc[0] * invN, s1 = sc[1] * invN;
  float mx = fmaxf(s0, s1);
  float e0 = expf(s0 - mx), e1 = expf(s1 - mx);
  float inv = 1.0f / (e0 + e1);
  float z = e0 * inv * m0[i] + e1 * inv * m1[i];
  out[i] = cheb ? (2.0f * z - Tx0[i]) : z;
}

// eta[n] = (1/32) sum_r tanh(Tx[n]·projW[kidx][:,r] + projb[kidx][r]) * gamma[r][kidx]
// hidden[n][c] (+)= Tx[n][c]*eta[n]
__global__ void k_gpr(const float* __restrict__ Tx, const float* __restrict__ projW,
                      const float* __restrict__ projb, const float* __restrict__ gamma,
                      int kidx, float* __restrict__ hidden, int N, int accum) {
  int row = blockIdx.x * 4 + (threadIdx.x >> 6);
  int lane = threadIdx.x & 63;
  if (row >= N) return;
  const float* tx = Tx + (size_t)row * 64;
  float part = 0.f;
  if (lane < 32) {
    const float* pw = projW + (size_t)kidx * (64 * 32);
    float acc = projb[kidx * 32 + lane];
#pragma unroll
    for (int k = 0; k < 64; ++k) acc = fmaf(tx[k], pw[k * 32 + lane], acc);
    part = tanhf(acc) * gamma[lane * (KORD + 1) + kidx];
  }
  part = waveSum(part);
  float eta = part * (1.0f / RANKC);
  size_t o = (size_t)row * 64 + lane;
  float val = tx[lane] * eta;
  hidden[o] = accum ? (hidden[o] + val) : val;
}

// C = H @ H^T, H is N x 64, 64x64 tiles, 4x4 per thread
__global__ __launch_bounds__(256) void k_adj(const float* __restrict__ H,
                                             float* __restrict__ C, int N) {
  __shared__ float As[64][65];
  __shared__ float Bs[64][65];
  int bi = blockIdx.x, bj = blockIdx.y;
  int tid = threadIdx.x;
#pragma unroll
  for (int l = 0; l < 16; ++l) {
    int flat = l * 256 + tid;
    int i = flat >> 6, k = flat & 63;
    int gi = bi * 64 + i;
    int gj = bj * 64 + i;
    As[i][k] = (gi < N) ? H[(size_t)gi * 64 + k] : 0.f;
    Bs[i][k] = (gj < N) ? H[(size_t)gj * 64 + k] : 0.f;
  }
  __syncthreads();
  int tx = tid & 15, ty = tid >> 4;
  int r0 = ty * 4, c0 = tx * 4;
  float acc[4][4] = {};
#pragma unroll 8
  for (int k = 0; k < 64; ++k) {
    float a0 = As[r0 + 0][k], a1 = As[r0 + 1][k], a2 = As[r0 + 2][k], a3 = As[r0 + 3][k];
    float b0 = Bs[c0 + 0][k], b1 = Bs[c0 + 1][k], b2 = Bs[c0 + 2][k], b3 = Bs[c0 + 3][k];
    acc[0][0] = fmaf(a0, b0, acc[0][0]); acc[0][1] = fmaf(a0, b1, acc[0][1]);
    acc[0][2] = fmaf(a0, b2, acc[0][2]); acc[0][3] = fmaf(a0, b3, acc[0][3]);
    acc[1][0] = fmaf(a1, b0, acc[1][0]); acc[1][1] = fmaf(a1, b1, acc[1][1]);
    acc[1][2] = fmaf(a1, b2, acc[1][2]); acc[1][3] = fmaf(a1, b3, acc[1][3]);
    acc[2][0] = fmaf(a2, b0, acc[2][0]); acc[2][1] = fmaf(a2, b1, acc[2][1]);
    acc[2][2] = fmaf(a2, b2, acc[2][2]); acc[2][3] = fmaf(a2, b3, acc[2][3]);
    acc[3][0] = fmaf(a3, b0, acc[3][0]); acc[3][1] = fmaf(a3, b1, acc[3][1]);
    acc[3][2] = fmaf(a3, b2, acc[3][2]); acc[3][3] = fmaf(a3, b3, acc[3][3]);
  }
  int grow = bi * 64 + r0, gcol = bj * 64 + c0;
#pragma unroll
  for (int m = 0; m < 4; ++m) {
    int gr = grow + m;
    if (gr >= N) break;
    if (gcol + 3 < N) {
      float4 val = make_float4(acc[m][0], acc[m][1], acc[m][2], acc[m][3]);
      *reinterpret_cast<float4*>(&C[(size_t)gr * N + gcol]) = val;
    } else {
      for (int n2 = 0; n2 < 4; ++n2)
        if (gcol + n2 < N) C[(size_t)gr * N + gcol + n2] = acc[m][n2];
    }
  }
}

// one row per block; out[row][c] = act(X[row]·W[:,c] + b[c])
template<int K>
__global__ void k_rowgemm(const float* __restrict__ X, const float* __restrict__ W,
                          const float* __restrict__ b, float* __restrict__ out,
                          int NCOL, int act) {
  __shared__ float xs[K];
  int row = blockIdx.x;
  for (int k = threadIdx.x; k < K; k += blockDim.x) xs[k] = X[(size_t)row * K + k];
  __syncthreads();
  for (int c = threadIdx.x; c < NCOL; c += blockDim.x) {
    float acc = b[c];
#pragma unroll 4
    for (int k = 0; k < K; ++k) acc = fmaf(xs[k], W[k * NCOL + c], acc);
    if (act == 1) acc = fmaxf(acc, 0.f);
    else if (act == 2) acc = tanhf(acc);
    out[(size_t)row * NCOL + c] = acc;
  }
}

__global__ void k_tanhv(const float* __restrict__ in, float* __restrict__ out, int n) {
  int i = blockIdx.x * blockDim.x + threadIdx.x;
  if (i < n) out[i] = tanhf(in[i]);
}

__global__ void k_loss(const float* __restrict__ h, const float* __restrict__ zp,
                       float* __restrict__ accum, int N) {
  int row = blockIdx.x * 4 + (threadIdx.x >> 6);
  int lane = threadIdx.x & 63;
  if (row >= N) return;
  float hv = h[(size_t)row * 64 + lane];
  float zv = zp[(size_t)row * 64 + lane];
  float hm = waveSum(hv) * (1.0f / 64.0f);
  float zm = waveSum(zv) * (1.0f / 64.0f);
  float c = waveSum((hv - hm) * (zv - zm)) * (1.0f / 64.0f);
  if (lane == 0) atomicAdd(accum, c);
}

__global__ void k_finalize(const float* __restrict__ accum, float* __restrict__ out) {
  float s = accum[0] * (1.0f / NT);
  out[0] = s * s;  // loss_dis1 (1-row HSIC) is exactly 0
}

__global__ void k_logits(const float* __restrict__ h, const float* __restrict__ W,
                         const float* __restrict__ b, float* __restrict__ out, int N) {
  int i = blockIdx.x * blockDim.x + threadIdx.x;
  if (i >= N * 3) return;
  int n = i / 3, j = i % 3;
  const float* hr = h + (size_t)n * 64;
  float acc = b[j];
#pragma unroll
  for (int c = 0; c < 64; ++c) acc = fmaf(hr[c], W[c * 3 + j], acc);
  out[i] = acc;
}

extern "C" void kernel_launch(void* const* d_in, const int* in_sizes, int n_in,
                              void* d_out, int out_size, void* d_ws, size_t ws_size,
                              hipStream_t stream) {
  const float* features_v1 = (const float*)d_in[0];
  const float* feat_other  = (const float*)d_in[1];
  const float* z_pre = (const float*)d_in[2];
  const float* Wt = (const float*)d_in[3];   const float* bt = (const float*)d_in[4];
  const float* Wo = (const float*)d_in[5];   const float* bo = (const float*)d_in[6];
  const float* W1r0 = (const float*)d_in[7];  const float* b1r0 = (const float*)d_in[8];
  const float* W1r1 = (const float*)d_in[9];  const float* b1r1 = (const float*)d_in[10];
  const float* W1r2 = (const float*)d_in[11]; const float* b1r2 = (const float*)d_in[12];
  const float* att1_fcW = (const float*)d_in[13]; const float* att1_fcb = (const float*)d_in[14];
  const float* att1_v = (const float*)d_in[15];
  const float* W2r0 = (const float*)d_in[16]; const float* b2r0 = (const float*)d_in[17];
  // W2r1/b2r1 (d_in[18]/d_in[19]) only feed the discarded out_o in the loop — unused.
  const float* W2r2 = (const float*)d_in[20]; const float* b2r2 = (const float*)d_in[21];
  const float* att2_fcW = (const float*)d_in[22]; const float* att2_fcb = (const float*)d_in[23];
  const float* att2_v = (const float*)d_in[24];
  const float* projW = (const float*)d_in[25]; const float* projb = (const float*)d_in[26];
  const float* gamma = (const float*)d_in[27];
  const float* p3W = (const float*)d_in[28]; const float* p3b = (const float*)d_in[29];
  const float* p1W1 = (const float*)d_in[30]; const float* p1b1 = (const float*)d_in[31];
  const float* p1W2 = (const float*)d_in[32]; const float* p1b2 = (const float*)d_in[33];
  const float* outW = (const float*)d_in[34]; const float* outb = (const float*)d_in[35];
  const int* src_r0 = (const int*)d_in[36]; const int* dst_r0 = (const int*)d_in[37];
  const int* src_r1 = (const int*)d_in[38]; const int* dst_r1 = (const int*)d_in[39];
  const int* src_r2 = (const int*)d_in[40]; const int* dst_r2 = (const int*)d_in[41];

  float* out = (float*)d_out;
  const size_t LOGITS_OFF = 0;
  const size_t H_OFF = (size_t)NT * 3;                    // 36000
  const size_t XPRE_OFF = H_OFF + (size_t)NT * 64;        // 804000
  const size_t ZPRE_OFF = XPRE_OFF + (size_t)NT * 334;    // 4812000
  const size_t ADJ_OFF = ZPRE_OFF + (size_t)NT * 334;     // 8820000
  const size_t LOSS_OFF = ADJ_OFF + (size_t)NT * NT;      // 152820000

  float* ws = (float*)d_ws;
  size_t o = 0;
  auto alloc = [&](size_t n) { float* p = ws + o; o += n; return p; };
  float* Tx0_t = alloc((size_t)NT * 64);
  float* Tx1_t = alloc((size_t)NT * 64);
  float* Tx2_t = alloc((size_t)NT * 64);
  float* Tx0_o = alloc((size_t)NO * 64);
  float* Tx1_o = alloc((size_t)NO * 64);
  float* mt0   = alloc((size_t)NT * 64);
  float* mt2   = alloc((size_t)NT * 64);
  float* agg_t = alloc((size_t)NT * 64);
  float* agg_o = alloc((size_t)NO * 64);
  float* hidden = alloc((size_t)NT * 64);
  float* zp    = alloc((size_t)NT * 64);
  float* t1    = alloc((size_t)NT * 128);
  float* rs_s0 = alloc(NO);   // degree arrays, contiguous (96000 floats)
  float* rs_d0 = alloc(NT);
  float* rs_s1 = alloc(NT);
  float* rs_d1 = alloc(NO);
  float* rs_s2 = alloc(NT);
  float* rs_d2 = alloc(NT);
  float* sc = alloc(8);       // sc[0],sc[1]: att scores; sc[2]: loss accum

  const int BT = 256;
  const int gNT = NT / 4;   // 3000 blocks (exact)
  const int gNO = NO / 4;   // 6000 blocks (exact)

  // ---- degree / normalization (constant per call) ----
  hipMemsetAsync(rs_s0, 0, (96000 + 8) * sizeof(float), stream);
  k_deg<<<(E0C + BT - 1) / BT, BT, 0, stream>>>(src_r0, rs_s0, E0C);
  k_deg<<<(E0C + BT - 1) / BT, BT, 0, stream>>>(dst_r0, rs_d0, E0C);
  k_deg<<<(E1C + BT - 1) / BT, BT, 0, stream>>>(src_r1, rs_s1, E1C);
  k_deg<<<(E1C + BT - 1) / BT, BT, 0, stream>>>(dst_r1, rs_d1, E1C);
  k_deg<<<(E2C + BT - 1) / BT, BT, 0, stream>>>(src_r2, rs_s2, E2C);
  k_deg<<<(E2C + BT - 1) / BT, BT, 0, stream>>>(dst_r2, rs_d2, E2C);
  k_rs<<<96000 / BT, BT, 0, stream>>>(rs_s0, 96000);

  // ---- input projections ----
  k_gemmN64<334><<<gNT, BT, 0, stream>>>(features_v1, Wt, bt, Tx0_t, NT);
  k_gemmN64<128><<<gNO, BT, 0, stream>>>(feat_other, Wo, bo, Tx0_o, NO);

  // ---- layer 1 hconv ----
  hipMemsetAsync(agg_t, 0, (size_t)NT * 64 * sizeof(float), stream);
  k_scatter<<<4096, BT, 0, stream>>>(Tx0_o, rs_s0, src_r0, dst_r0, agg_t, E0C);
  k_gemm64s<<<gNT, BT, 0, stream>>>(agg_t, rs_d0, W1r0, b1r0, mt0, NT);
  hipMemsetAsync(agg_t, 0, (size_t)NT * 64 * sizeof(float), stream);
  k_scatter<<<4096, BT, 0, stream>>>(Tx0_t, rs_s2, src_r2, dst_r2, agg_t, E2C);
  k_gemm64s<<<gNT, BT, 0, stream>>>(agg_t, rs_d2, W1r2, b1r2, mt2, NT);
  hipMemsetAsync(agg_o, 0, (size_t)NO * 64 * sizeof(float), stream);
  k_scatter<<<4096, BT, 0, stream>>>(Tx0_t, rs_s1, src_r1, dst_r1, agg_o, E1C);
  k_gemm64s<<<gNO, BT, 0, stream>>>(agg_o, rs_d1, W1r1, b1r1, Tx1_o, NO);  // out_o == m_o

  hipMemsetAsync(sc, 0, 2 * sizeof(float), stream);
  k_attscore<<<gNT, BT, 0, stream>>>(mt0, att1_fcW, att1_fcb, att1_v, sc + 0, NT);
  k_attscore<<<gNT, BT, 0, stream>>>(mt2, att1_fcW, att1_fcb, att1_v, sc + 1, NT);
  k_combine<<<(NT * 64 + BT - 1) / BT, BT, 0, stream>>>(mt0, mt2, sc, 1.0f / NT, mt0,
                                                        Tx1_t, NT * 64, 0);

  // hidden = Tx0*eta0 + Tx1*eta1
  k_gpr<<<gNT, BT, 0, stream>>>(Tx0_t, projW, projb, gamma, 0, hidden, NT, 0);
  k_gpr<<<gNT, BT, 0, stream>>>(Tx1_t, projW, projb, gamma, 1, hidden, NT, 1);

  // ---- loop-invariant m_t0 (layer 2) + its att score ----
  hipMemsetAsync(agg_t, 0, (size_t)NT * 64 * sizeof(float), stream);
  k_scatter<<<4096, BT, 0, stream>>>(Tx1_o, rs_s0, src_r0, dst_r0, agg_t, E0C);
  k_gemm64s<<<gNT, BT, 0, stream>>>(agg_t, rs_d0, W2r0, b2r0, mt0, NT);
  hipMemsetAsync(sc, 0, sizeof(float), stream);
  k_attscore<<<gNT, BT, 0, stream>>>(mt0, att2_fcW, att2_fcb, att2_v, sc + 0, NT);

  // ---- GPR propagation loop ----
  for (int k = 1; k < KORD; ++k) {
    hipMemsetAsync(agg_t, 0, (size_t)NT * 64 * sizeof(float), stream);
    k_scatter<<<4096, BT, 0, stream>>>(Tx1_t, rs_s2, src_r2, dst_r2, agg_t, E2C);
    k_gemm64s<<<gNT, BT, 0, stream>>>(agg_t, rs_d2, W2r2, b2r2, mt2, NT);
    hipMemsetAsync(sc + 1, 0, sizeof(float), stream);
    k_attscore<<<gNT, BT, 0, stream>>>(mt2, att2_fcW, att2_fcb, att2_v, sc + 1, NT);
    k_combine<<<(NT * 64 + BT - 1) / BT, BT, 0, stream>>>(mt0, mt2, sc, 1.0f / NT, Tx0_t,
                                                          Tx2_t, NT * 64, 1);
    float* tmp = Tx0_t; Tx0_t = Tx1_t; Tx1_t = Tx2_t; Tx2_t = tmp;
    k_gpr<<<gNT, BT, 0, stream>>>(Tx1_t, projW, projb, gamma, k + 1, hidden, NT, 1);
  }

  // ---- finals ----
  dim3 adjGrid((NT + 63) / 64, (NT + 63) / 64);
  k_adj<<<adjGrid, 256, 0, stream>>>(hidden, out + ADJ_OFF, NT);
  k_tanhv<<<(NT * 64 + BT - 1) / BT, BT, 0, stream>>>(hidden, out + H_OFF, NT * 64);
  k_gemmN64<128><<<gNT, BT, 0, stream>>>(z_pre, p3W, p3b, zp, NT);

  hipMemsetAsync(sc + 2, 0, sizeof(float), stream);
  k_loss<<<gNT, BT, 0, stream>>>(out + H_OFF, zp, sc + 2, NT);
  k_finalize<<<1, 1, 0, stream>>>(sc + 2, out + LOSS_OFF);

  k_rowgemm<64><<<NT, 128, 0, stream>>>(out + H_OFF, p1W1, p1b1, t1, 128, 1);
  k_rowgemm<128><<<NT, 256, 0, stream>>>(t1, p1W2, p1b2, out + XPRE_OFF, 334, 2);
  k_rowgemm<64><<<NT, 128, 0, stream>>>(zp, p1W1, p1b1, t1, 128, 1);
  k_rowgemm<128><<<NT, 256, 0, stream>>>(t1, p1W2, p1b2, out + ZPRE_OFF, 334, 2);
  k_logits<<<(NT * 3 + BT - 1) / BT, BT, 0, stream>>>(out + H_OFF, outW, outb,
                                                      out + LOGITS_OFF, NT);
}